// Round 1
// baseline (1068.732 us; speedup 1.0000x reference)
//
#include <hip/hip_runtime.h>

#define B 2
#define S 2048
#define D 768
#define H 12
#define DH 64
#define TOPK 512
#define NROW (B*S)   // 4096

// ---------------------------------------------------------------------------
// Tiled fp32 GEMM: C = A (N x K) @ W^T (W is M x K, row-major) + bias, * scale
// MODE 0: C row-major [N][M]   (final output projection)
// MODE 1: C as [b][h][s][dh]   (QKV projections, head-split layout)
// ---------------------------------------------------------------------------
template<int MODE>
__global__ __launch_bounds__(256) void proj_kernel(
    const float* __restrict__ A, const float* __restrict__ W,
    const float* __restrict__ bias, float* __restrict__ C, float scale) {
  __shared__ __align__(16) float As[16][68];
  __shared__ __align__(16) float Bs[16][68];
  int tid = threadIdx.x;
  int tx = tid & 15, ty = tid >> 4;
  int rowBase = blockIdx.x * 64;
  int colBase = blockIdx.y * 64;
  float acc[4][4] = {};
  for (int k0 = 0; k0 < D; k0 += 16) {
#pragma unroll
    for (int r = 0; r < 4; ++r) {
      int e = tid + 256*r;
      int row = e >> 4, kk = e & 15;
      As[kk][row] = A[(size_t)(rowBase + row)*D + k0 + kk];
      Bs[kk][row] = W[(size_t)(colBase + row)*D + k0 + kk];
    }
    __syncthreads();
#pragma unroll
    for (int kk = 0; kk < 16; ++kk) {
      float4 a4 = *(const float4*)&As[kk][ty*4];
      float4 b4 = *(const float4*)&Bs[kk][tx*4];
      float av[4] = {a4.x, a4.y, a4.z, a4.w};
      float bv[4] = {b4.x, b4.y, b4.z, b4.w};
#pragma unroll
      for (int i = 0; i < 4; ++i)
#pragma unroll
        for (int j = 0; j < 4; ++j)
          acc[i][j] += av[i]*bv[j];
    }
    __syncthreads();
  }
#pragma unroll
  for (int i = 0; i < 4; ++i) {
#pragma unroll
    for (int j = 0; j < 4; ++j) {
      int n = rowBase + ty*4 + i;
      int m = colBase + tx*4 + j;
      float val = (acc[i][j] + bias[m]) * scale;
      if (MODE == 0) {
        C[(size_t)n*D + m] = val;
      } else {
        int b = n / S, s = n % S, hh = m >> 6, dh = m & 63;
        C[(((size_t)b*H + hh)*S + s)*DH + dh] = val;
      }
    }
  }
}

// ---------------------------------------------------------------------------
// Leverage stage A1: per-head partial KtK over 128-row chunks (batch 0 only)
// partials[(h*16+blk)][64][64]
// ---------------------------------------------------------------------------
__global__ __launch_bounds__(256) void levA1_kernel(
    const float* __restrict__ Kmat, float* __restrict__ partials) {
  int h = blockIdx.x, blk = blockIdx.y;
  __shared__ __align__(16) float ktile[128*64];
  int tid = threadIdx.x;
  const float* Kh = Kmat + ((size_t)h*S + (size_t)blk*128)*DH;
#pragma unroll
  for (int r = 0; r < 32; ++r) { int e = tid + 256*r; ktile[e] = Kh[e]; }
  __syncthreads();
  int j4 = tid & 15;
  float accf[4][4] = {};
  for (int ss = 0; ss < 128; ++ss) {
    float4 kj = ((const float4*)(ktile + ss*64))[j4];
#pragma unroll
    for (int r = 0; r < 4; ++r) {
      int i = (tid >> 4) + 16*r;
      float ki = ktile[ss*64 + i];
      accf[r][0] += ki*kj.x; accf[r][1] += ki*kj.y;
      accf[r][2] += ki*kj.z; accf[r][3] += ki*kj.w;
    }
  }
  size_t base = ((size_t)h*16 + blk)*4096;
#pragma unroll
  for (int r = 0; r < 4; ++r) {
    int i = (tid >> 4) + 16*r;
#pragma unroll
    for (int c = 0; c < 4; ++c)
      partials[base + (size_t)i*64 + j4*4 + c] = accf[r][c];
  }
}

// ---------------------------------------------------------------------------
// Leverage stage A2: fp64 reduce of partials + damping, then fp32
// Gauss-Jordan inverse of the 64x64 SPD matrix. One block per head.
// ---------------------------------------------------------------------------
__global__ __launch_bounds__(256) void levA2_kernel(
    const float* __restrict__ partials, float* __restrict__ invOut) {
  int h = blockIdx.x, tid = threadIdx.x;
  __shared__ float aug[64*128];
  __shared__ float fcol[64];
#pragma unroll
  for (int r = 0; r < 16; ++r) {
    int e = tid + 256*r; int i = e >> 6, j = e & 63;
    double a = 0.0;
    for (int p = 0; p < 16; ++p)
      a += (double)partials[((size_t)h*16 + p)*4096 + (size_t)i*64 + j];
    if (i == j) a += 1e-6;
    aug[i*128 + j] = (float)a;
    aug[i*128 + 64 + j] = (i == j) ? 1.0f : 0.0f;
  }
  __syncthreads();
  for (int p = 0; p < 64; ++p) {
    if (tid < 64) fcol[tid] = aug[tid*128 + p];
    __syncthreads();
    float pivInv = 1.0f / fcol[p];
    if (tid < 128) aug[p*128 + tid] *= pivInv;
    __syncthreads();
#pragma unroll
    for (int r = 0; r < 32; ++r) {
      int e = tid + 256*r;
      int row = e >> 7, c = e & 127;
      if (row != p) aug[e] -= fcol[row] * aug[p*128 + c];
    }
    __syncthreads();
  }
#pragma unroll
  for (int r = 0; r < 16; ++r) {
    int e = tid + 256*r; int i = e >> 6, j = e & 63;
    invOut[(size_t)h*4096 + i*64 + j] = aug[i*128 + 64 + j];
  }
}

// ---------------------------------------------------------------------------
// Leverage stage B: lev[h][s] = k_s^T inv_h k_s
// ---------------------------------------------------------------------------
__global__ __launch_bounds__(256) void levB_kernel(
    const float* __restrict__ Kmat, const float* __restrict__ invMat,
    float* __restrict__ lev) {
  int h = blockIdx.x;
  int s = blockIdx.y*256 + threadIdx.x;
  __shared__ __align__(16) float inv[64*64];
#pragma unroll
  for (int r = 0; r < 16; ++r)
    inv[threadIdx.x + 256*r] = invMat[(size_t)h*4096 + threadIdx.x + 256*r];
  __syncthreads();
  float kv[64];
  const float* kr = Kmat + ((size_t)h*S + s)*DH;
#pragma unroll
  for (int d4 = 0; d4 < 16; ++d4) {
    float4 t = ((const float4*)kr)[d4];
    kv[4*d4+0]=t.x; kv[4*d4+1]=t.y; kv[4*d4+2]=t.z; kv[4*d4+3]=t.w;
  }
  float acc = 0.f;
  for (int i = 0; i < 64; ++i) {
    float ti = 0.f;
    const float4* ir = (const float4*)(inv + i*64);
#pragma unroll
    for (int j4 = 0; j4 < 16; ++j4) {
      float4 iv = ir[j4];
      ti += iv.x*kv[4*j4] + iv.y*kv[4*j4+1] + iv.z*kv[4*j4+2] + iv.w*kv[4*j4+3];
    }
    acc += ti * kv[i];
  }
  lev[(size_t)h*S + s] = acc;
}

// ---------------------------------------------------------------------------
// Top-k via full bitonic sort of 2048 (value desc, index asc on ties —
// matches jax.lax.top_k stability). One block per head.
// ---------------------------------------------------------------------------
__global__ __launch_bounds__(256) void topk_kernel(
    const float* __restrict__ lev, int* __restrict__ idx_list) {
  int h = blockIdx.x, tid = threadIdx.x;
  __shared__ float sv[2048];
  __shared__ int   si[2048];
#pragma unroll
  for (int r = 0; r < 8; ++r) {
    int e = tid + 256*r;
    sv[e] = lev[(size_t)h*S + e];
    si[e] = e;
  }
  __syncthreads();
  for (int k = 2; k <= 2048; k <<= 1) {
    for (int j = k >> 1; j > 0; j >>= 1) {
      for (int r = 0; r < 8; ++r) {
        int i = tid + 256*r;
        int l = i ^ j;
        if (l > i) {
          float v1 = sv[i], v2 = sv[l];
          int   i1 = si[i], i2 = si[l];
          bool before = (v1 > v2) || (v1 == v2 && i1 < i2);
          bool dir = ((i & k) == 0);
          if (before != dir) { sv[i]=v2; sv[l]=v1; si[i]=i2; si[l]=i1; }
        }
      }
      __syncthreads();
    }
  }
#pragma unroll
  for (int r = 0; r < 2; ++r) {
    int t = tid + 256*r;
    idx_list[h*TOPK + t] = si[t];
  }
}

// ---------------------------------------------------------------------------
// Gather kept K/V rows into compact [b][h][512][64] buffers
// ---------------------------------------------------------------------------
__global__ __launch_bounds__(256) void gather_kernel(
    const float* __restrict__ Kmat, const float* __restrict__ Vmat,
    const int* __restrict__ idx_list,
    float* __restrict__ KC, float* __restrict__ VC) {
  int g = blockIdx.x*256 + threadIdx.x;
  int d = g & 63;
  int t = g >> 6;
  int j = t & 511;
  int bh = t >> 9;
  int h = bh % H;
  int s = idx_list[h*TOPK + j];
  size_t src = ((size_t)bh*S + s)*DH + d;
  KC[g] = Kmat[src];
  VC[g] = Vmat[src];
}

// ---------------------------------------------------------------------------
// Attention: single pass. ctx = (sum_j sq_j * v_j) / (sum_j sq_j + 1e-12)
// (normalization is linear -> no second pass). One thread per query row.
// ---------------------------------------------------------------------------
__global__ __launch_bounds__(128) void attn_kernel(
    const float* __restrict__ Q, const float* __restrict__ KC,
    const float* __restrict__ VC, float* __restrict__ CTX) {
  __shared__ __align__(16) float kt[64*64];
  __shared__ __align__(16) float vt[64*64];
  int tid = threadIdx.x;
  int bid = blockIdx.x;
  int qt = bid & 15;
  int bh = bid >> 4;
  int b = bh / H, h = bh % H;
  int qrow = qt*128 + tid;
  const float* qp = Q + ((size_t)bh*S + qrow)*DH;
  float qreg[64];
#pragma unroll
  for (int d4 = 0; d4 < 16; ++d4) {
    float4 t4 = ((const float4*)qp)[d4];
    qreg[4*d4+0]=t4.x; qreg[4*d4+1]=t4.y; qreg[4*d4+2]=t4.z; qreg[4*d4+3]=t4.w;
  }
  float ctx[64] = {};
  float z = 0.f;
  for (int t0 = 0; t0 < TOPK; t0 += 64) {
#pragma unroll
    for (int r = 0; r < 32; ++r) {
      int e = tid + 128*r;
      kt[e] = KC[((size_t)bh*TOPK + t0)*DH + e];
      vt[e] = VC[((size_t)bh*TOPK + t0)*DH + e];
    }
    __syncthreads();
    for (int jj = 0; jj < 64; ++jj) {
      const float4* krow = (const float4*)(kt + jj*64);
      float dot = 0.f;
#pragma unroll
      for (int d4 = 0; d4 < 16; ++d4) {
        float4 k4 = krow[d4];
        dot += qreg[4*d4+0]*k4.x + qreg[4*d4+1]*k4.y
             + qreg[4*d4+2]*k4.z + qreg[4*d4+3]*k4.w;
      }
      float sq = dot*dot;
      z += sq;
      const float4* vrow = (const float4*)(vt + jj*64);
#pragma unroll
      for (int d4 = 0; d4 < 16; ++d4) {
        float4 v4 = vrow[d4];
        ctx[4*d4+0] += sq*v4.x; ctx[4*d4+1] += sq*v4.y;
        ctx[4*d4+2] += sq*v4.z; ctx[4*d4+3] += sq*v4.w;
      }
    }
    __syncthreads();
  }
  float zi = 1.0f / (z + 1e-12f);
  float* cp = CTX + ((size_t)b*S + qrow)*D + h*DH;
#pragma unroll
  for (int d = 0; d < 64; ++d) cp[d] = ctx[d]*zi;
}

// ---------------------------------------------------------------------------
extern "C" void kernel_launch(void* const* d_in, const int* in_sizes, int n_in,
                              void* d_out, int out_size, void* d_ws, size_t ws_size,
                              hipStream_t stream) {
  const float* query = (const float*)d_in[0];
  const float* key   = (const float*)d_in[1];
  const float* value = (const float*)d_in[2];
  const float* Wq = (const float*)d_in[3];
  const float* bq = (const float*)d_in[4];
  const float* Wk = (const float*)d_in[5];
  const float* bk = (const float*)d_in[6];
  const float* Wv = (const float*)d_in[7];
  const float* bv = (const float*)d_in[8];
  const float* Wo = (const float*)d_in[9];
  const float* bo = (const float*)d_in[10];
  float* out = (float*)d_out;

  float* ws = (float*)d_ws;
  const size_t QKV = (size_t)B*H*S*DH;        // 3,145,728
  float* Qws   = ws;
  float* Kws   = Qws + QKV;
  float* Vws   = Kws + QKV;
  float* CTXws = Vws + QKV;
  float* partials = CTXws + QKV;              // H*16*4096 = 786,432
  float* invWs = partials + (size_t)H*16*4096;// H*4096    = 49,152
  float* levWs = invWs + (size_t)H*4096;      // H*2048    = 24,576
  float* KCws  = levWs + (size_t)H*S;         // 786,432
  float* VCws  = KCws + (size_t)B*H*TOPK*DH;  // 786,432
  int*   idxWs = (int*)(VCws + (size_t)B*H*TOPK*DH);

  dim3 pgrid(NROW/64, D/64);
  proj_kernel<1><<<pgrid, 256, 0, stream>>>(query, Wq, bq, Qws, 0.125f);
  proj_kernel<1><<<pgrid, 256, 0, stream>>>(key,   Wk, bk, Kws, 1.0f);
  proj_kernel<1><<<pgrid, 256, 0, stream>>>(value, Wv, bv, Vws, 1.0f);

  levA1_kernel<<<dim3(H,16), 256, 0, stream>>>(Kws, partials);
  levA2_kernel<<<H, 256, 0, stream>>>(partials, invWs);
  levB_kernel<<<dim3(H,8), 256, 0, stream>>>(Kws, invWs, levWs);
  topk_kernel<<<H, 256, 0, stream>>>(levWs, idxWs);

  gather_kernel<<<(B*H*TOPK*DH)/256, 256, 0, stream>>>(Kws, Vws, idxWs, KCws, VCws);

  attn_kernel<<<B*H*(S/128), 128, 0, stream>>>(Qws, KCws, VCws, CTXws);

  proj_kernel<0><<<pgrid, 256, 0, stream>>>(CTXws, Wo, bo, out, 1.0f);
}

// Round 2
// 601.965 us; speedup vs baseline: 1.7754x; 1.7754x over previous
//
#include <hip/hip_runtime.h>

#define B 2
#define S 2048
#define D 768
#define H 12
#define DH 64
#define TOPK 512
#define NROW (B*S)   // 4096

typedef __attribute__((ext_vector_type(8))) short bf16x8;
typedef __attribute__((ext_vector_type(8))) ushort u16x8;
typedef __attribute__((ext_vector_type(4))) float f32x4;

// ---- bf16 split helpers (hi = RNE bf16 of x, lo = RNE bf16 of residual) ----
__device__ __forceinline__ ushort bf16_hi(float x) {
  union { float f; unsigned u; } v; v.f = x;
  unsigned r = v.u + 0x7fffu + ((v.u >> 16) & 1u);
  return (ushort)(r >> 16);
}
__device__ __forceinline__ float bf16_tof(ushort h) {
  union { float f; unsigned u; } v; v.u = ((unsigned)h) << 16; return v.f;
}
__device__ __forceinline__ void bf16_split(float x, ushort& h, ushort& l) {
  h = bf16_hi(x);
  l = bf16_hi(x - bf16_tof(h));
}

// ---------------------------------------------------------------------------
// Tiled fp32 GEMM: C = A (N x K) @ W^T (W is M x K, row-major) + bias, * scale
// MODE 0: C row-major [N][M]   (final output projection)
// MODE 1: C as [b][h][s][dh]   (QKV projections, head-split layout)
// ---------------------------------------------------------------------------
template<int MODE>
__global__ __launch_bounds__(256) void proj_kernel(
    const float* __restrict__ A, const float* __restrict__ W,
    const float* __restrict__ bias, float* __restrict__ C, float scale) {
  __shared__ __align__(16) float As[16][68];
  __shared__ __align__(16) float Bs[16][68];
  int tid = threadIdx.x;
  int tx = tid & 15, ty = tid >> 4;
  int rowBase = blockIdx.x * 64;
  int colBase = blockIdx.y * 64;
  float acc[4][4] = {};
  for (int k0 = 0; k0 < D; k0 += 16) {
#pragma unroll
    for (int r = 0; r < 4; ++r) {
      int e = tid + 256*r;
      int row = e >> 4, kk = e & 15;
      As[kk][row] = A[(size_t)(rowBase + row)*D + k0 + kk];
      Bs[kk][row] = W[(size_t)(colBase + row)*D + k0 + kk];
    }
    __syncthreads();
#pragma unroll
    for (int kk = 0; kk < 16; ++kk) {
      float4 a4 = *(const float4*)&As[kk][ty*4];
      float4 b4 = *(const float4*)&Bs[kk][tx*4];
      float av[4] = {a4.x, a4.y, a4.z, a4.w};
      float bv[4] = {b4.x, b4.y, b4.z, b4.w};
#pragma unroll
      for (int i = 0; i < 4; ++i)
#pragma unroll
        for (int j = 0; j < 4; ++j)
          acc[i][j] += av[i]*bv[j];
    }
    __syncthreads();
  }
#pragma unroll
  for (int i = 0; i < 4; ++i) {
#pragma unroll
    for (int j = 0; j < 4; ++j) {
      int n = rowBase + ty*4 + i;
      int m = colBase + tx*4 + j;
      float val = (acc[i][j] + bias[m]) * scale;
      if (MODE == 0) {
        C[(size_t)n*D + m] = val;
      } else {
        int b = n / S, s = n % S, hh = m >> 6, dh = m & 63;
        C[(((size_t)b*H + hh)*S + s)*DH + dh] = val;
      }
    }
  }
}

// ---------------------------------------------------------------------------
// Leverage stage A1: per-head partial KtK over 128-row chunks (batch 0 only)
// ---------------------------------------------------------------------------
__global__ __launch_bounds__(256) void levA1_kernel(
    const float* __restrict__ Kmat, float* __restrict__ partials) {
  int h = blockIdx.x, blk = blockIdx.y;
  __shared__ __align__(16) float ktile[128*64];
  int tid = threadIdx.x;
  const float* Kh = Kmat + ((size_t)h*S + (size_t)blk*128)*DH;
#pragma unroll
  for (int r = 0; r < 32; ++r) { int e = tid + 256*r; ktile[e] = Kh[e]; }
  __syncthreads();
  int j4 = tid & 15;
  float accf[4][4] = {};
  for (int ss = 0; ss < 128; ++ss) {
    float4 kj = ((const float4*)(ktile + ss*64))[j4];
#pragma unroll
    for (int r = 0; r < 4; ++r) {
      int i = (tid >> 4) + 16*r;
      float ki = ktile[ss*64 + i];
      accf[r][0] += ki*kj.x; accf[r][1] += ki*kj.y;
      accf[r][2] += ki*kj.z; accf[r][3] += ki*kj.w;
    }
  }
  size_t base = ((size_t)h*16 + blk)*4096;
#pragma unroll
  for (int r = 0; r < 4; ++r) {
    int i = (tid >> 4) + 16*r;
#pragma unroll
    for (int c = 0; c < 4; ++c)
      partials[base + (size_t)i*64 + j4*4 + c] = accf[r][c];
  }
}

// ---------------------------------------------------------------------------
// Leverage stage A2: fp64 reduce + Gauss-Jordan 64x64 inverse, 1 block/head
// ---------------------------------------------------------------------------
__global__ __launch_bounds__(256) void levA2_kernel(
    const float* __restrict__ partials, float* __restrict__ invOut) {
  int h = blockIdx.x, tid = threadIdx.x;
  __shared__ float aug[64*128];
  __shared__ float fcol[64];
#pragma unroll
  for (int r = 0; r < 16; ++r) {
    int e = tid + 256*r; int i = e >> 6, j = e & 63;
    double a = 0.0;
    for (int p = 0; p < 16; ++p)
      a += (double)partials[((size_t)h*16 + p)*4096 + (size_t)i*64 + j];
    if (i == j) a += 1e-6;
    aug[i*128 + j] = (float)a;
    aug[i*128 + 64 + j] = (i == j) ? 1.0f : 0.0f;
  }
  __syncthreads();
  for (int p = 0; p < 64; ++p) {
    if (tid < 64) fcol[tid] = aug[tid*128 + p];
    __syncthreads();
    float pivInv = 1.0f / fcol[p];
    if (tid < 128) aug[p*128 + tid] *= pivInv;
    __syncthreads();
#pragma unroll
    for (int r = 0; r < 32; ++r) {
      int e = tid + 256*r;
      int row = e >> 7, c = e & 127;
      if (row != p) aug[e] -= fcol[row] * aug[p*128 + c];
    }
    __syncthreads();
  }
#pragma unroll
  for (int r = 0; r < 16; ++r) {
    int e = tid + 256*r; int i = e >> 6, j = e & 63;
    invOut[(size_t)h*4096 + i*64 + j] = aug[i*128 + 64 + j];
  }
}

// ---------------------------------------------------------------------------
// Leverage stage B: lev[h][s] = k_s^T inv_h k_s
// ---------------------------------------------------------------------------
__global__ __launch_bounds__(256) void levB_kernel(
    const float* __restrict__ Kmat, const float* __restrict__ invMat,
    float* __restrict__ lev) {
  int h = blockIdx.x;
  int s = blockIdx.y*256 + threadIdx.x;
  __shared__ __align__(16) float inv[64*64];
#pragma unroll
  for (int r = 0; r < 16; ++r)
    inv[threadIdx.x + 256*r] = invMat[(size_t)h*4096 + threadIdx.x + 256*r];
  __syncthreads();
  float kv[64];
  const float* kr = Kmat + ((size_t)h*S + s)*DH;
#pragma unroll
  for (int d4 = 0; d4 < 16; ++d4) {
    float4 t = ((const float4*)kr)[d4];
    kv[4*d4+0]=t.x; kv[4*d4+1]=t.y; kv[4*d4+2]=t.z; kv[4*d4+3]=t.w;
  }
  float acc = 0.f;
  for (int i = 0; i < 64; ++i) {
    float ti = 0.f;
    const float4* ir = (const float4*)(inv + i*64);
#pragma unroll
    for (int j4 = 0; j4 < 16; ++j4) {
      float4 iv = ir[j4];
      ti += iv.x*kv[4*j4] + iv.y*kv[4*j4+1] + iv.z*kv[4*j4+2] + iv.w*kv[4*j4+3];
    }
    acc += ti * kv[i];
  }
  lev[(size_t)h*S + s] = acc;
}

// ---------------------------------------------------------------------------
// Top-k via bitonic sort (value desc, index asc)
// ---------------------------------------------------------------------------
__global__ __launch_bounds__(256) void topk_kernel(
    const float* __restrict__ lev, int* __restrict__ idx_list) {
  int h = blockIdx.x, tid = threadIdx.x;
  __shared__ float sv[2048];
  __shared__ int   si[2048];
#pragma unroll
  for (int r = 0; r < 8; ++r) {
    int e = tid + 256*r;
    sv[e] = lev[(size_t)h*S + e];
    si[e] = e;
  }
  __syncthreads();
  for (int k = 2; k <= 2048; k <<= 1) {
    for (int j = k >> 1; j > 0; j >>= 1) {
      for (int r = 0; r < 8; ++r) {
        int i = tid + 256*r;
        int l = i ^ j;
        if (l > i) {
          float v1 = sv[i], v2 = sv[l];
          int   i1 = si[i], i2 = si[l];
          bool before = (v1 > v2) || (v1 == v2 && i1 < i2);
          bool dir = ((i & k) == 0);
          if (before != dir) { sv[i]=v2; sv[l]=v1; si[i]=i2; si[l]=i1; }
        }
      }
      __syncthreads();
    }
  }
#pragma unroll
  for (int r = 0; r < 2; ++r) {
    int t = tid + 256*r;
    idx_list[h*TOPK + t] = si[t];
  }
}

// ---------------------------------------------------------------------------
// Gather kept K/V rows -> bf16 split buffers.
// KCh/KCl: [bh][512][64]  (row-major, keys x dh)
// VCth/VCtl: [bh][64][512] (TRANSPOSED: dh x keys) for contiguous PV B-frags
// One block per (bh, 64-key chunk).
// ---------------------------------------------------------------------------
__global__ __launch_bounds__(256) void gather_kernel(
    const float* __restrict__ Kmat, const float* __restrict__ Vmat,
    const int* __restrict__ idx_list,
    ushort* __restrict__ KCh, ushort* __restrict__ KCl,
    ushort* __restrict__ VCth, ushort* __restrict__ VCtl) {
  int bh = blockIdx.x;        // 0..23
  int kc = blockIdx.y;        // 0..7
  int h = bh % H;
  __shared__ float vt[64][65];
  int tid = threadIdx.x;
  int kk = tid >> 2;           // key within chunk (0..63)
  int dq = (tid & 3) * 16;     // dh base (0,16,32,48)
  int j = kc*64 + kk;
  int srow = idx_list[h*TOPK + j];
  const float* kr = Kmat + ((size_t)bh*S + srow)*DH + dq;
  const float* vr = Vmat + ((size_t)bh*S + srow)*DH + dq;
  ushort hh[16], ll[16];
#pragma unroll
  for (int i = 0; i < 16; ++i) bf16_split(kr[i], hh[i], ll[i]);
  size_t kbase = ((size_t)bh*TOPK + j)*DH + dq;
  *(u16x8*)(KCh + kbase)     = *(u16x8*)&hh[0];
  *(u16x8*)(KCh + kbase + 8) = *(u16x8*)&hh[8];
  *(u16x8*)(KCl + kbase)     = *(u16x8*)&ll[0];
  *(u16x8*)(KCl + kbase + 8) = *(u16x8*)&ll[8];
#pragma unroll
  for (int i = 0; i < 16; ++i) vt[kk][dq + i] = vr[i];
  __syncthreads();
  int d  = tid >> 2;           // dh row (0..63)
  int kq = (tid & 3) * 16;     // key base within chunk
#pragma unroll
  for (int i = 0; i < 16; ++i) bf16_split(vt[kq + i][d], hh[i], ll[i]);
  size_t vbase = ((size_t)bh*DH + d)*TOPK + kc*64 + kq;
  *(u16x8*)(VCth + vbase)     = *(u16x8*)&hh[0];
  *(u16x8*)(VCth + vbase + 8) = *(u16x8*)&hh[8];
  *(u16x8*)(VCtl + vbase)     = *(u16x8*)&ll[0];
  *(u16x8*)(VCtl + vbase + 8) = *(u16x8*)&ll[8];
}

// ---------------------------------------------------------------------------
// MFMA attention, split-bf16 (~fp32 accurate): single pass.
// Block: 256 threads = 4 waves; each wave owns 16 query rows.
// Per 64-key chunk: scores via mfma(Q,K) (3 split MFMAs), square + fp32
// row-sum z (shfl reduce), sq -> LDS (bf16 split, padded stride 88) to
// transpose into PV A-frags; PV via mfma(SQ,V) (3 split MFMAs).
// No __syncthreads in main loop: LDS regions are wave-private.
// ---------------------------------------------------------------------------
__global__ __launch_bounds__(256) void attn_kernel(
    const float* __restrict__ Q,
    const ushort* __restrict__ KCh, const ushort* __restrict__ KCl,
    const ushort* __restrict__ VCth, const ushort* __restrict__ VCtl,
    float* __restrict__ CTX) {
  __shared__ __align__(16) ushort SQh[4][16][88];
  __shared__ __align__(16) ushort SQl[4][16][88];
  int tid = threadIdx.x;
  int w = tid >> 6;
  int lane = tid & 63;
  int lr = lane & 15, lg = lane >> 4;
  int bh = blockIdx.x >> 5;
  int qt = blockIdx.x & 31;
  int qbase = qt*64 + w*16;
  int b = bh / H, h = bh % H;

  // Q A-fragments (hi/lo), loaded once: lane -> row lr, k = ks*32 + lg*8
  bf16x8 qh[2], ql[2];
#pragma unroll
  for (int ks = 0; ks < 2; ++ks) {
    const float* qp = Q + ((size_t)bh*S + qbase + lr)*DH + ks*32 + lg*8;
    float qv[8];
    *(float4*)&qv[0] = *(const float4*)qp;
    *(float4*)&qv[4] = *(const float4*)(qp + 4);
#pragma unroll
    for (int i = 0; i < 8; ++i) {
      ushort hh, lo; bf16_split(qv[i], hh, lo);
      qh[ks][i] = (short)hh; ql[ks][i] = (short)lo;
    }
  }

  f32x4 pacc[4] = {};
  float z_acc[4] = {};

  for (int c = 0; c < 8; ++c) {
    int keybase = c*64;
    // ---- scores: 64 queries(x16 per wave) x 64 keys ----
    f32x4 sacc[4] = {};
#pragma unroll
    for (int ks = 0; ks < 2; ++ks) {
#pragma unroll
      for (int f = 0; f < 4; ++f) {
        size_t koff = ((size_t)bh*TOPK + keybase + 16*f + lr)*DH + ks*32 + lg*8;
        bf16x8 kh = *(const bf16x8*)(KCh + koff);
        bf16x8 kl = *(const bf16x8*)(KCl + koff);
        sacc[f] = __builtin_amdgcn_mfma_f32_16x16x32_bf16(qh[ks], kh, sacc[f], 0, 0, 0);
        sacc[f] = __builtin_amdgcn_mfma_f32_16x16x32_bf16(qh[ks], kl, sacc[f], 0, 0, 0);
        sacc[f] = __builtin_amdgcn_mfma_f32_16x16x32_bf16(ql[ks], kh, sacc[f], 0, 0, 0);
      }
    }
    // ---- square, fp32 z partials, sq -> LDS (bf16 split) ----
    float zc[4] = {};
#pragma unroll
    for (int f = 0; f < 4; ++f) {
#pragma unroll
      for (int r = 0; r < 4; ++r) {
        float s = sacc[f][r];
        float sq = s*s;
        zc[r] += sq;
        ushort hh, lo; bf16_split(sq, hh, lo);
        SQh[w][lg*4 + r][16*f + lr] = hh;
        SQl[w][lg*4 + r][16*f + lr] = lo;
      }
    }
#pragma unroll
    for (int r = 0; r < 4; ++r) {
      float t = zc[r];
      t += __shfl_xor(t, 1);
      t += __shfl_xor(t, 2);
      t += __shfl_xor(t, 4);
      t += __shfl_xor(t, 8);
      z_acc[r] += t;
    }
    // ---- PV: ctx += SQ @ V ----
#pragma unroll
    for (int ks = 0; ks < 2; ++ks) {
      bf16x8 ah = *(const bf16x8*)&SQh[w][lr][ks*32 + lg*8];
      bf16x8 al = *(const bf16x8*)&SQl[w][lr][ks*32 + lg*8];
#pragma unroll
      for (int f = 0; f < 4; ++f) {
        size_t voff = ((size_t)bh*DH + 16*f + lr)*TOPK + keybase + ks*32 + lg*8;
        bf16x8 vh = *(const bf16x8*)(VCth + voff);
        bf16x8 vl = *(const bf16x8*)(VCtl + voff);
        pacc[f] = __builtin_amdgcn_mfma_f32_16x16x32_bf16(ah, vh, pacc[f], 0, 0, 0);
        pacc[f] = __builtin_amdgcn_mfma_f32_16x16x32_bf16(ah, vl, pacc[f], 0, 0, 0);
        pacc[f] = __builtin_amdgcn_mfma_f32_16x16x32_bf16(al, vh, pacc[f], 0, 0, 0);
      }
    }
  }

  float zi[4];
#pragma unroll
  for (int r = 0; r < 4; ++r) zi[r] = 1.0f / (z_acc[r] + 1e-12f);
#pragma unroll
  for (int f = 0; f < 4; ++f) {
#pragma unroll
    for (int r = 0; r < 4; ++r) {
      int q = lg*4 + r;
      float val = pacc[f][r] * zi[r];
      CTX[((size_t)b*S + qbase + q)*D + h*DH + 16*f + lr] = val;
    }
  }
}

// ---------------------------------------------------------------------------
extern "C" void kernel_launch(void* const* d_in, const int* in_sizes, int n_in,
                              void* d_out, int out_size, void* d_ws, size_t ws_size,
                              hipStream_t stream) {
  const float* query = (const float*)d_in[0];
  const float* key   = (const float*)d_in[1];
  const float* value = (const float*)d_in[2];
  const float* Wq = (const float*)d_in[3];
  const float* bq = (const float*)d_in[4];
  const float* Wk = (const float*)d_in[5];
  const float* bk = (const float*)d_in[6];
  const float* Wv = (const float*)d_in[7];
  const float* bv = (const float*)d_in[8];
  const float* Wo = (const float*)d_in[9];
  const float* bo = (const float*)d_in[10];
  float* out = (float*)d_out;

  float* ws = (float*)d_ws;
  const size_t QKV = (size_t)B*H*S*DH;        // 3,145,728
  float* Qws   = ws;
  float* Kws   = Qws + QKV;
  float* Vws   = Kws + QKV;
  float* CTXws = Vws + QKV;
  float* partials = CTXws + QKV;              // H*16*4096 = 786,432
  float* invWs = partials + (size_t)H*16*4096;// H*4096
  float* levWs = invWs + (size_t)H*4096;      // H*2048
  ushort* KCh  = (ushort*)(levWs + (size_t)H*S);
  ushort* KCl  = KCh  + (size_t)B*H*TOPK*DH;  // 786,432 each
  ushort* VCth = KCl  + (size_t)B*H*TOPK*DH;
  ushort* VCtl = VCth + (size_t)B*H*TOPK*DH;
  int*   idxWs = (int*)(VCtl + (size_t)B*H*TOPK*DH);

  dim3 pgrid(NROW/64, D/64);
  proj_kernel<1><<<pgrid, 256, 0, stream>>>(query, Wq, bq, Qws, 0.125f);
  proj_kernel<1><<<pgrid, 256, 0, stream>>>(key,   Wk, bk, Kws, 1.0f);
  proj_kernel<1><<<pgrid, 256, 0, stream>>>(value, Wv, bv, Vws, 1.0f);

  levA1_kernel<<<dim3(H,16), 256, 0, stream>>>(Kws, partials);
  levA2_kernel<<<H, 256, 0, stream>>>(partials, invWs);
  levB_kernel<<<dim3(H,8), 256, 0, stream>>>(Kws, invWs, levWs);
  topk_kernel<<<H, 256, 0, stream>>>(levWs, idxWs);

  gather_kernel<<<dim3(B*H, TOPK/64), 256, 0, stream>>>(
      Kws, Vws, idxWs, KCh, KCl, VCth, VCtl);

  attn_kernel<<<B*H*(S/64), 256, 0, stream>>>(Qws, KCh, KCl, VCth, VCtl, CTXws);

  proj_kernel<0><<<pgrid, 256, 0, stream>>>(CTXws, Wo, bo, out, 1.0f);
}